// Round 13
// baseline (430.250 us; speedup 1.0000x reference)
//
#include <hip/hip_runtime.h>
#include <math.h>

#define NBATCH 8192
#define NNODE  25
#define DIN    256
#define NH     8
#define NF     32
#define HF     256
#define NE     48
#define NT     73     // NE + NNODE self loops
#define NEG_SLOPE 0.2f

// d_ws: [0,139264) bf16 Waug frags (17*8*64*8 shorts);
//       [139264, +4096) f32 lnm[32][32]: log(edge multiplicity), -1e30 if absent
#define WS_LNM_OFF 139264

typedef __bf16 bf16x8 __attribute__((ext_vector_type(8)));
typedef float  f32x4  __attribute__((ext_vector_type(4)));

static __device__ __forceinline__ unsigned short f2bf(float f) {
    unsigned int u = __float_as_uint(f);
    return (unsigned short)((u + 0x7fffu + ((u >> 16) & 1u)) >> 16);
}

static __device__ __forceinline__ float bpermf(int idxb, float v) {
    return __int_as_float(__builtin_amdgcn_ds_bpermute(idxb, __float_as_int(v)));
}

static __device__ __forceinline__ void gload_lds16(const void* g, void* l) {
    __builtin_amdgcn_global_load_lds(
        (const __attribute__((address_space(1))) void*)g,
        (__attribute__((address_space(3))) void*)l, 16, 0, 0);
}

// ---- prep: pack Waug B-frags (verified r2-r12) + lnm table (verified r6-r12) ----
__global__ void prep(const float* __restrict__ W,
                     const float* __restrict__ a_src,
                     const float* __restrict__ a_dst,
                     const int*   __restrict__ edges,
                     unsigned short* __restrict__ wf,
                     float* __restrict__ lnm) {
    const int blk = blockIdx.x;
    if (blk < 34) {
        const int tid  = blk * 256 + threadIdx.x;   // 0..8703 == 17*8*64
        const int lane = tid & 63;
        const int ks   = (tid >> 6) & 7;
        const int ct   = tid >> 9;
        const int k0   = ks * 32 + (lane >> 4) * 8;
        if (ct < 16) {
            const int col = ct * 16 + (lane & 15);
#pragma unroll
            for (int j = 0; j < 8; ++j)
                wf[tid * 8 + j] = f2bf(W[(k0 + j) * HF + col]);
        } else {
            // tile 16: Waug[k][0..7]=W·a_src per head, [8..15]=W·a_dst per head.
            const int hp = lane & 15;
            const float* av = (hp < 8) ? (a_src + hp * NF) : (a_dst + (hp - 8) * NF);
            const int wc = (hp & 7) * NF;
#pragma unroll
            for (int j = 0; j < 8; ++j) {
                float s = 0.f;
                for (int f = 0; f < NF; ++f)
                    s = fmaf(W[(k0 + j) * HF + wc + f], av[f], s);
                wf[tid * 8 + j] = f2bf(s);
            }
        }
    } else {
        // dense log-multiplicity adjacency: lnm[d][s]
        __shared__ int cnt[32 * 32];
        const int t = threadIdx.x;
        for (int i = t; i < 1024; i += 256) cnt[i] = 0;
        __syncthreads();
        if (t < NT) {
            const int s = (t < NE) ? edges[t]      : (t - NE);
            const int d = (t < NE) ? edges[NE + t] : (t - NE);
            atomicAdd(&cnt[d * 32 + s], 1);
        }
        __syncthreads();
        for (int i = t; i < 1024; i += 256) {
            const int c = cnt[i];
            lnm[i] = (c > 0) ? logf((float)c) : -1e30f;
        }
    }
}

// ---- main: PERSISTENT workgroups. 512 WGs x 512 threads = 2 WGs/CU, all
//      resident. Stage the half's 8 W-tiles + logits tile (72 KB) ONCE,
//      then each wave loops over 4 batches with NO barriers in the loop.
//      Loop body = r12-verified per-batch code. ----
__global__ __launch_bounds__(512, 2)
void gat_persist(const float* __restrict__ X,
                 const unsigned short* __restrict__ wf,
                 const float* __restrict__ lnm,
                 const float* __restrict__ bias,
                 float* __restrict__ out)
{
    __shared__ __align__(16) unsigned char sWf[73728];   // 8 col-tiles + logits tile
    const int t    = threadIdx.x;
    const int wid  = t >> 6;
    const int l    = t & 63;
    const int g    = blockIdx.x;                  // 0..511
    const int half = g & 1;                       // 0: heads 0-3/tiles 0-7; 1: heads 4-7/tiles 8-15
    const int slot = (g >> 1) * 8 + wid;          // 0..2047
    const int r    = l & 15;
    const int kq   = l >> 4;
    const int kqa  = kq & 1;
    const bool hiSel = (kq >> 1) != 0;

    // bpermute byte-index bases (r8-verified)
    const int idx_as_base = kqa * 32;             // + (h>>2)*64 + 4j
    const int idx_ad_base = 128 + r * 4;          // + (h>>2)*64
    const int idx_h_base  = (kqa * 32 + r) * 4;   // + (j>>2)*64

    // ---- stage once: half's 8 tiles (64 KB) + logits tile (8 KB) ----
    {
        const unsigned char* wfb = (const unsigned char*)wf;
#pragma unroll
        for (int i = 0; i < 8; ++i)
            gload_lds16(wfb + half * 65536 + i * 8192 + t * 16, sWf + i * 8192 + t * 16);
        gload_lds16(wfb + 131072 + t * 16, sWf + 65536 + t * 16);
    }

    // ---- adjacency log-mults resident: lnm[d=dstt*16+r][s=kq*8+j] ----
    const f32x4 lnA0 = *(const f32x4*)(lnm + r * 32 + kq * 8);
    const f32x4 lnA1 = *(const f32x4*)(lnm + r * 32 + kq * 8 + 4);
    const f32x4 lnB0 = *(const f32x4*)(lnm + (16 + r) * 32 + kq * 8);
    const f32x4 lnB1 = *(const f32x4*)(lnm + (16 + r) * 32 + kq * 8 + 4);

    __syncthreads();   // staged wf visible; no barriers after this

#pragma unroll 1
    for (int it = 0; it < 4; ++it) {
        const int b = slot + it * 2048;

        // ---- A-frags from global (r8-verified): af{m}[ks] = X[16m+r][ks*32+kq*8 ..+7] ----
        bf16x8 af0[8], af1[8];
        const float* Xb = X + (size_t)b * (NNODE * DIN);
        {
            const float* xp0 = Xb + r * DIN + kq * 8;
#pragma unroll
            for (int ks = 0; ks < 8; ++ks) {
                const f32x4 x0 = *(const f32x4*)(xp0 + ks * 32);
                const f32x4 x1 = *(const f32x4*)(xp0 + ks * 32 + 4);
                bf16x8 v;
                v[0]=(__bf16)x0[0]; v[1]=(__bf16)x0[1]; v[2]=(__bf16)x0[2]; v[3]=(__bf16)x0[3];
                v[4]=(__bf16)x1[0]; v[5]=(__bf16)x1[1]; v[6]=(__bf16)x1[2]; v[7]=(__bf16)x1[3];
                af0[ks] = v;
            }
            const bool valid = r < 9;             // rows 16+r must be < 25
            const float zm = valid ? 1.f : 0.f;
            const float* xp1 = Xb + (valid ? (16 + r) : r) * DIN + kq * 8;
#pragma unroll
            for (int ks = 0; ks < 8; ++ks) {
                const f32x4 x0 = *(const f32x4*)(xp1 + ks * 32);
                const f32x4 x1 = *(const f32x4*)(xp1 + ks * 32 + 4);
                bf16x8 v;
                v[0]=(__bf16)(x0[0]*zm); v[1]=(__bf16)(x0[1]*zm); v[2]=(__bf16)(x0[2]*zm); v[3]=(__bf16)(x0[3]*zm);
                v[4]=(__bf16)(x1[0]*zm); v[5]=(__bf16)(x1[1]*zm); v[6]=(__bf16)(x1[2]*zm); v[7]=(__bf16)(x1[3]*zm);
                af1[ks] = v;
            }
        }

        // ---- logits (r8-verified), B-frag now from LDS: accL{m}[q] = L[16m+r][4kq+q] ----
        f32x4 accL0 = {0.f, 0.f, 0.f, 0.f};
        f32x4 accL1 = {0.f, 0.f, 0.f, 0.f};
#pragma unroll
        for (int ks = 0; ks < 8; ++ks) {
            const bf16x8 wa = *(const bf16x8*)(sWf + 65536 + ks * 1024 + l * 16);
            accL0 = __builtin_amdgcn_mfma_f32_16x16x32_bf16(wa, af0[ks], accL0, 0, 0, 0);
            accL1 = __builtin_amdgcn_mfma_f32_16x16x32_bf16(wa, af1[ks], accL1, 0, 0, 0);
        }

        float* ob = out + (size_t)b * (NNODE * HF);

#pragma unroll
        for (int hh = 0; hh < 4; ++hh) {
            const int h = half * 4 + hh;
            // ---- softmax for head h (r8-verified) ----
            const int hb2 = (h >> 2) * 64;
            const int q   = h & 3;
            const float ad0 = bpermf(idx_ad_base + hb2, accL0[q]);   // L[d=r][8+h]
            const float ad1 = bpermf(idx_ad_base + hb2, accL1[q]);   // L[d=16+r][8+h]
            float e0[8], e1[8];
            float s0 = 0.f, s1 = 0.f;
#pragma unroll
            for (int j = 0; j < 8; ++j) {
                const int ia = idx_as_base + hb2 + j * 4;
                const float v0 = bpermf(ia, accL0[q]);
                const float v1 = bpermf(ia, accL1[q]);
                const float asj = hiSel ? v1 : v0;      // as[s = kq*8+j][h]
                const float ln0j = (j < 4) ? lnA0[j & 3] : lnA1[j & 3];
                const float ln1j = (j < 4) ? lnB0[j & 3] : lnB1[j & 3];
                float t0 = asj + ad0; t0 = (t0 > 0.f) ? t0 : NEG_SLOPE * t0;
                float t1 = asj + ad1; t1 = (t1 > 0.f) ? t1 : NEG_SLOPE * t1;
                e0[j] = __expf(t0 + ln0j);              // mult * exp(leaky), 0 if no edge
                e1[j] = __expf(t1 + ln1j);
                s0 += e0[j]; s1 += e1[j];
            }
            s0 += __shfl_xor(s0, 16); s0 += __shfl_xor(s0, 32);
            s1 += __shfl_xor(s1, 16); s1 += __shfl_xor(s1, 32);
            const float i0 = 1.f / (s0 + 1e-16f);
            const float i1 = 1.f / (s1 + 1e-16f);
            bf16x8 pf0, pf1;
#pragma unroll
            for (int j = 0; j < 8; ++j) {
                pf0[j] = (__bf16)(e0[j] * i0);
                pf1[j] = (__bf16)(e1[j] * i1);
            }

            // ---- two 16-col feature tiles of this head (B-frags from LDS) ----
#pragma unroll
            for (int cc = 0; cc < 2; ++cc) {
                const int ct  = 2 * h + cc;             // in [half*8, half*8+8)
                const int lct = ct - half * 8;
                // GEMM1: h columns ct*16..+15. acc{m}[q'] = h[16m+4kq+q'][ct*16+r]
                f32x4 a0 = {0.f, 0.f, 0.f, 0.f};
                f32x4 a1 = {0.f, 0.f, 0.f, 0.f};
#pragma unroll
                for (int ks = 0; ks < 8; ++ks) {
                    const bf16x8 bw = *(const bf16x8*)(sWf + ((lct * 8 + ks) * 64 + l) * 16);
                    a0 = __builtin_amdgcn_mfma_f32_16x16x32_bf16(af0[ks], bw, a0, 0, 0, 0);
                    a1 = __builtin_amdgcn_mfma_f32_16x16x32_bf16(af1[ks], bw, a1, 0, 0, 0);
                }
                // redistribute -> GEMM2 A-frag: hf[j] = h[s = kq*8+j][feat = ct*16+r]
                bf16x8 hf;
#pragma unroll
                for (int j = 0; j < 8; ++j) {
                    const int ih = idx_h_base + (j >> 2) * 64;
                    const float v0 = bpermf(ih, a0[j & 3]);
                    const float v1 = bpermf(ih, a1[j & 3]);
                    hf[j] = (__bf16)(hiSel ? v1 : v0);
                }
                // GEMM2: out^T tile = h^T · P^T (+bias as C-in), K=32 one-shot
                const f32x4 bv = *(const f32x4*)(bias + ct * 16 + kq * 4);
                f32x4 o0 = bv, o1 = bv;
                o0 = __builtin_amdgcn_mfma_f32_16x16x32_bf16(hf, pf0, o0, 0, 0, 0);
                o1 = __builtin_amdgcn_mfma_f32_16x16x32_bf16(hf, pf1, o1, 0, 0, 0);
                // D[row = feat-in-tile 4kq+q'][col = dst r] -> out[b][dst][16ct+4kq+q']
                *(f32x4*)(ob + r * HF + ct * 16 + kq * 4) = o0;
                if (r < 9)
                    *(f32x4*)(ob + (16 + r) * HF + ct * 16 + kq * 4) = o1;
            }
        }
    }
}

extern "C" void kernel_launch(void* const* d_in, const int* in_sizes, int n_in,
                              void* d_out, int out_size, void* d_ws, size_t ws_size,
                              hipStream_t stream) {
    const float* X     = (const float*)d_in[0];
    const float* W     = (const float*)d_in[1];
    const float* a_src = (const float*)d_in[2];
    const float* a_dst = (const float*)d_in[3];
    const float* bias  = (const float*)d_in[4];
    const int*   edges = (const int*)d_in[5];
    float* out = (float*)d_out;
    unsigned short* wf = (unsigned short*)d_ws;
    float* lnm = (float*)((unsigned char*)d_ws + WS_LNM_OFF);

    hipLaunchKernelGGL(prep, dim3(35), dim3(256), 0, stream,
                       W, a_src, a_dst, edges, wf, lnm);
    hipLaunchKernelGGL(gat_persist, dim3(512), dim3(512), 0, stream,
                       X, wf, lnm, bias, out);
}

// Round 14
// 244.736 us; speedup vs baseline: 1.7580x; 1.7580x over previous
//
#include <hip/hip_runtime.h>
#include <math.h>

#define NBATCH 8192
#define NNODE  25
#define DIN    256
#define NH     8
#define NF     32
#define HF     256
#define NE     48
#define NT     73     // NE + NNODE self loops
#define NEG_SLOPE 0.2f

// d_ws: [0,139264) bf16 Waug frags (17*8*64*8 shorts);
//       [139264, +4096) f32 lnm[32][32]: log(edge multiplicity), -1e30 if absent
#define WS_LNM_OFF 139264

typedef __bf16 bf16x8 __attribute__((ext_vector_type(8)));
typedef float  f32x4  __attribute__((ext_vector_type(4)));

static __device__ __forceinline__ unsigned short f2bf(float f) {
    unsigned int u = __float_as_uint(f);
    return (unsigned short)((u + 0x7fffu + ((u >> 16) & 1u)) >> 16);
}

static __device__ __forceinline__ float bpermf(int idxb, float v) {
    return __int_as_float(__builtin_amdgcn_ds_bpermute(idxb, __float_as_int(v)));
}

// ---- K0: in-situ memory-floor probe. Pure float4 copy X -> d_out (m13
//      pattern, exact problem volume). d_out is fully overwritten by the
//      main kernel afterwards -> correctness unaffected, deterministic.
//      rocprof attributes its duration separately = the true floor. ----
__global__ __launch_bounds__(256)
void memfloor_probe(const float4* __restrict__ src, float4* __restrict__ dst, int n4) {
    const int stride = gridDim.x * blockDim.x;
    for (int i = blockIdx.x * blockDim.x + threadIdx.x; i < n4; i += stride)
        dst[i] = src[i];
}

// ---- prep: pack Waug B-frags (verified r2-r13) + lnm table (verified r6-r13) ----
__global__ void prep(const float* __restrict__ W,
                     const float* __restrict__ a_src,
                     const float* __restrict__ a_dst,
                     const int*   __restrict__ edges,
                     unsigned short* __restrict__ wf,
                     float* __restrict__ lnm) {
    const int blk = blockIdx.x;
    if (blk < 34) {
        const int tid  = blk * 256 + threadIdx.x;   // 0..8703 == 17*8*64
        const int lane = tid & 63;
        const int ks   = (tid >> 6) & 7;
        const int ct   = tid >> 9;
        const int k0   = ks * 32 + (lane >> 4) * 8;
        if (ct < 16) {
            const int col = ct * 16 + (lane & 15);
#pragma unroll
            for (int j = 0; j < 8; ++j)
                wf[tid * 8 + j] = f2bf(W[(k0 + j) * HF + col]);
        } else {
            // tile 16: Waug[k][0..7]=W·a_src per head, [8..15]=W·a_dst per head.
            const int hp = lane & 15;
            const float* av = (hp < 8) ? (a_src + hp * NF) : (a_dst + (hp - 8) * NF);
            const int wc = (hp & 7) * NF;
#pragma unroll
            for (int j = 0; j < 8; ++j) {
                float s = 0.f;
                for (int f = 0; f < NF; ++f)
                    s = fmaf(W[(k0 + j) * HF + wc + f], av[f], s);
                wf[tid * 8 + j] = f2bf(s);
            }
        }
    } else {
        // dense log-multiplicity adjacency: lnm[d][s]
        __shared__ int cnt[32 * 32];
        const int t = threadIdx.x;
        for (int i = t; i < 1024; i += 256) cnt[i] = 0;
        __syncthreads();
        if (t < NT) {
            const int s = (t < NE) ? edges[t]      : (t - NE);
            const int d = (t < NE) ? edges[NE + t] : (t - NE);
            atomicAdd(&cnt[d * 32 + s], 1);
        }
        __syncthreads();
        for (int i = t; i < 1024; i += 256) {
            const int c = cnt[i];
            lnm[i] = (c > 0) ? logf((float)c) : -1e30f;
        }
    }
}

// ---- main: r8 verbatim (best: 158 us). One wave = one batch; 4 waves/WG;
//      no LDS, no barriers; launch_bounds(256,3). ----
__global__ __launch_bounds__(256, 3)
void gat_wave(const float* __restrict__ X,
              const unsigned short* __restrict__ wf,
              const float* __restrict__ lnm,
              const float* __restrict__ bias,
              float* __restrict__ out)
{
    const int t   = threadIdx.x;
    const int l   = t & 63;
    const int b   = blockIdx.x * 4 + (t >> 6);
    const int r   = l & 15;
    const int kq  = l >> 4;
    const int kqa = kq & 1;
    const bool hiSel = (kq >> 1) != 0;   // m-half of node index s = kq*8+j

    // bpermute byte-index bases (lane_src * 4)
    const int idx_as_base = kqa * 32;            // + (h>>2)*64 + 4j
    const int idx_ad_base = 128 + r * 4;         // + (h>>2)*64
    const int idx_h_base  = (kqa * 32 + r) * 4;  // + (j>>2)*64

    // ---- A-frags straight from global: af{m}[ks] = X[16m+r][ks*32+kq*8 .. +7] ----
    bf16x8 af0[8], af1[8];
    const float* Xb = X + (size_t)b * (NNODE * DIN);
    {
        const float* xp0 = Xb + r * DIN + kq * 8;
#pragma unroll
        for (int ks = 0; ks < 8; ++ks) {
            const f32x4 x0 = *(const f32x4*)(xp0 + ks * 32);
            const f32x4 x1 = *(const f32x4*)(xp0 + ks * 32 + 4);
            bf16x8 v;
            v[0]=(__bf16)x0[0]; v[1]=(__bf16)x0[1]; v[2]=(__bf16)x0[2]; v[3]=(__bf16)x0[3];
            v[4]=(__bf16)x1[0]; v[5]=(__bf16)x1[1]; v[6]=(__bf16)x1[2]; v[7]=(__bf16)x1[3];
            af0[ks] = v;
        }
        const bool valid = r < 9;                 // rows 16+r must be < 25
        const float zm = valid ? 1.f : 0.f;
        const float* xp1 = Xb + (valid ? (16 + r) : r) * DIN + kq * 8;
#pragma unroll
        for (int ks = 0; ks < 8; ++ks) {
            const f32x4 x0 = *(const f32x4*)(xp1 + ks * 32);
            const f32x4 x1 = *(const f32x4*)(xp1 + ks * 32 + 4);
            bf16x8 v;
            v[0]=(__bf16)(x0[0]*zm); v[1]=(__bf16)(x0[1]*zm); v[2]=(__bf16)(x0[2]*zm); v[3]=(__bf16)(x0[3]*zm);
            v[4]=(__bf16)(x1[0]*zm); v[5]=(__bf16)(x1[1]*zm); v[6]=(__bf16)(x1[2]*zm); v[7]=(__bf16)(x1[3]*zm);
            af1[ks] = v;
        }
    }

    // ---- logits, swapped: L^T = Wa^T · X^T  =>  accL{m}[q] = L[16m+r][head-col 4kq+q] ----
    f32x4 accL0 = {0.f, 0.f, 0.f, 0.f};
    f32x4 accL1 = {0.f, 0.f, 0.f, 0.f};
#pragma unroll
    for (int ks = 0; ks < 8; ++ks) {
        const bf16x8 wa = *(const bf16x8*)(wf + ((size_t)(128 + ks) * 64 + l) * 8);
        accL0 = __builtin_amdgcn_mfma_f32_16x16x32_bf16(wa, af0[ks], accL0, 0, 0, 0);
        accL1 = __builtin_amdgcn_mfma_f32_16x16x32_bf16(wa, af1[ks], accL1, 0, 0, 0);
    }

    float* ob = out + (size_t)b * (NNODE * HF);

#pragma unroll
    for (int h = 0; h < 8; ++h) {
        // ---- adjacency log-mults reloaded per head (L2-hot) ----
        const f32x4 lnA0 = *(const f32x4*)(lnm + r * 32 + kq * 8);
        const f32x4 lnA1 = *(const f32x4*)(lnm + r * 32 + kq * 8 + 4);
        const f32x4 lnB0 = *(const f32x4*)(lnm + (16 + r) * 32 + kq * 8);
        const f32x4 lnB1 = *(const f32x4*)(lnm + (16 + r) * 32 + kq * 8 + 4);

        // ---- softmax for head h ----
        const int hb2 = (h >> 2) * 64;
        const int q   = h & 3;                      // static after unroll
        const float ad0 = bpermf(idx_ad_base + hb2, accL0[q]);   // L[d=r][8+h]
        const float ad1 = bpermf(idx_ad_base + hb2, accL1[q]);   // L[d=16+r][8+h]
        float e0[8], e1[8];
        float s0 = 0.f, s1 = 0.f;
#pragma unroll
        for (int j = 0; j < 8; ++j) {
            const int ia = idx_as_base + hb2 + j * 4;
            const float v0 = bpermf(ia, accL0[q]);
            const float v1 = bpermf(ia, accL1[q]);
            const float asj = hiSel ? v1 : v0;      // as[s = kq*8+j][h]
            const float ln0j = (j < 4) ? lnA0[j & 3] : lnA1[j & 3];
            const float ln1j = (j < 4) ? lnB0[j & 3] : lnB1[j & 3];
            float t0 = asj + ad0; t0 = (t0 > 0.f) ? t0 : NEG_SLOPE * t0;
            float t1 = asj + ad1; t1 = (t1 > 0.f) ? t1 : NEG_SLOPE * t1;
            e0[j] = __expf(t0 + ln0j);              // mult * exp(leaky), 0 if no edge
            e1[j] = __expf(t1 + ln1j);
            s0 += e0[j]; s1 += e1[j];
        }
        s0 += __shfl_xor(s0, 16); s0 += __shfl_xor(s0, 32);
        s1 += __shfl_xor(s1, 16); s1 += __shfl_xor(s1, 32);
        const float i0 = 1.f / (s0 + 1e-16f);
        const float i1 = 1.f / (s1 + 1e-16f);
        bf16x8 pf0, pf1;
#pragma unroll
        for (int j = 0; j < 8; ++j) {
            pf0[j] = (__bf16)(e0[j] * i0);
            pf1[j] = (__bf16)(e1[j] * i1);
        }

        // ---- two 16-col feature tiles of this head ----
#pragma unroll
        for (int cc = 0; cc < 2; ++cc) {
            const int ct = 2 * h + cc;
            // GEMM1: h columns ct*16..+15. acc{m}[q'] = h[16m+4kq+q'][ct*16+r]
            f32x4 a0 = {0.f, 0.f, 0.f, 0.f};
            f32x4 a1 = {0.f, 0.f, 0.f, 0.f};
#pragma unroll
            for (int ks = 0; ks < 8; ++ks) {
                const bf16x8 bw = *(const bf16x8*)(wf + ((size_t)(ct * 8 + ks) * 64 + l) * 8);
                a0 = __builtin_amdgcn_mfma_f32_16x16x32_bf16(af0[ks], bw, a0, 0, 0, 0);
                a1 = __builtin_amdgcn_mfma_f32_16x16x32_bf16(af1[ks], bw, a1, 0, 0, 0);
            }
            // redistribute -> GEMM2 A-frag: hf[j] = h[s = kq*8+j][feat = ct*16+r]
            bf16x8 hf;
#pragma unroll
            for (int j = 0; j < 8; ++j) {
                const int ih = idx_h_base + (j >> 2) * 64;
                const float v0 = bpermf(ih, a0[j & 3]);
                const float v1 = bpermf(ih, a1[j & 3]);
                hf[j] = (__bf16)(hiSel ? v1 : v0);
            }
            // GEMM2: out^T tile = h^T · P^T (+bias as C-in), K=32 one-shot
            const f32x4 bv = *(const f32x4*)(bias + ct * 16 + kq * 4);
            f32x4 o0 = bv, o1 = bv;
            o0 = __builtin_amdgcn_mfma_f32_16x16x32_bf16(hf, pf0, o0, 0, 0, 0);
            o1 = __builtin_amdgcn_mfma_f32_16x16x32_bf16(hf, pf1, o1, 0, 0, 0);
            // D[row = feat-in-tile 4kq+q'][col = dst r] -> out[b][dst][16ct+4kq+q']
            *(f32x4*)(ob + r * HF + ct * 16 + kq * 4) = o0;
            if (r < 9)
                *(f32x4*)(ob + (16 + r) * HF + ct * 16 + kq * 4) = o1;
        }
    }
}

extern "C" void kernel_launch(void* const* d_in, const int* in_sizes, int n_in,
                              void* d_out, int out_size, void* d_ws, size_t ws_size,
                              hipStream_t stream) {
    const float* X     = (const float*)d_in[0];
    const float* W     = (const float*)d_in[1];
    const float* a_src = (const float*)d_in[2];
    const float* a_dst = (const float*)d_in[3];
    const float* bias  = (const float*)d_in[4];
    const int*   edges = (const int*)d_in[5];
    float* out = (float*)d_out;
    unsigned short* wf = (unsigned short*)d_ws;
    float* lnm = (float*)((unsigned char*)d_ws + WS_LNM_OFF);

    // K0: memory-floor probe (d_out overwritten by gat_wave below)
    const int n4 = NBATCH * NNODE * DIN / 4;   // 13.1M float4 = 210 MB
    hipLaunchKernelGGL(memfloor_probe, dim3(2048), dim3(256), 0, stream,
                       (const float4*)X, (float4*)out, n4);
    hipLaunchKernelGGL(prep, dim3(35), dim3(256), 0, stream,
                       W, a_src, a_dst, edges, wf, lnm);
    hipLaunchKernelGGL(gat_wave, dim3(NBATCH / 4), dim3(256), 0, stream,
                       X, wf, lnm, bias, out);
}

// Round 15
// 146.116 us; speedup vs baseline: 2.9446x; 1.6749x over previous
//
#include <hip/hip_runtime.h>
#include <math.h>

#define NBATCH 8192
#define NNODE  25
#define DIN    256
#define NH     8
#define NF     32
#define HF     256
#define NE     48
#define NT     73     // NE + NNODE self loops
#define NEG_SLOPE 0.2f

// d_ws: [0,139264) bf16 Waug frags (17*8*64*8 shorts);
//       [139264, +4096) f32 lnm[32][32]: log(edge multiplicity), -1e30 if absent
#define WS_LNM_OFF 139264

typedef __bf16 bf16x8 __attribute__((ext_vector_type(8)));
typedef float  f32x4  __attribute__((ext_vector_type(4)));

static __device__ __forceinline__ unsigned short f2bf(float f) {
    unsigned int u = __float_as_uint(f);
    return (unsigned short)((u + 0x7fffu + ((u >> 16) & 1u)) >> 16);
}

static __device__ __forceinline__ float bpermf(int idxb, float v) {
    return __int_as_float(__builtin_amdgcn_ds_bpermute(idxb, __float_as_int(v)));
}

// ---- prep: pack Waug B-frags (verified r2-r14) + lnm table (verified r6-r14) ----
__global__ void prep(const float* __restrict__ W,
                     const float* __restrict__ a_src,
                     const float* __restrict__ a_dst,
                     const int*   __restrict__ edges,
                     unsigned short* __restrict__ wf,
                     float* __restrict__ lnm) {
    const int blk = blockIdx.x;
    if (blk < 34) {
        const int tid  = blk * 256 + threadIdx.x;   // 0..8703 == 17*8*64
        const int lane = tid & 63;
        const int ks   = (tid >> 6) & 7;
        const int ct   = tid >> 9;
        const int k0   = ks * 32 + (lane >> 4) * 8;
        if (ct < 16) {
            const int col = ct * 16 + (lane & 15);
#pragma unroll
            for (int j = 0; j < 8; ++j)
                wf[tid * 8 + j] = f2bf(W[(k0 + j) * HF + col]);
        } else {
            // tile 16: Waug[k][0..7]=W·a_src per head, [8..15]=W·a_dst per head.
            const int hp = lane & 15;
            const float* av = (hp < 8) ? (a_src + hp * NF) : (a_dst + (hp - 8) * NF);
            const int wc = (hp & 7) * NF;
#pragma unroll
            for (int j = 0; j < 8; ++j) {
                float s = 0.f;
                for (int f = 0; f < NF; ++f)
                    s = fmaf(W[(k0 + j) * HF + wc + f], av[f], s);
                wf[tid * 8 + j] = f2bf(s);
            }
        }
    } else {
        // dense log-multiplicity adjacency: lnm[d][s]
        __shared__ int cnt[32 * 32];
        const int t = threadIdx.x;
        for (int i = t; i < 1024; i += 256) cnt[i] = 0;
        __syncthreads();
        if (t < NT) {
            const int s = (t < NE) ? edges[t]      : (t - NE);
            const int d = (t < NE) ? edges[NE + t] : (t - NE);
            atomicAdd(&cnt[d * 32 + s], 1);
        }
        __syncthreads();
        for (int i = t; i < 1024; i += 256) {
            const int c = cnt[i];
            lnm[i] = (c > 0) ? logf((float)c) : -1e30f;
        }
    }
}

// ---- main: r8 structure + SOFTWARE PREFETCH of wf B-frags (K2's trick).
//      Two register buffers (even/odd ct); each tile's loads re-issued
//      ~800 cycles before consumption -> high MLP instead of per-tile
//      load->waitcnt->MFMA serialization. launch_bounds(256,2): room for
//      the ~190-reg live set without spill. ----
__global__ __launch_bounds__(256, 2)
void gat_wave(const float* __restrict__ X,
              const unsigned short* __restrict__ wf,
              const float* __restrict__ lnm,
              const float* __restrict__ bias,
              float* __restrict__ out)
{
    const int t   = threadIdx.x;
    const int l   = t & 63;
    const int b   = blockIdx.x * 4 + (t >> 6);
    const int r   = l & 15;
    const int kq  = l >> 4;
    const int kqa = kq & 1;
    const bool hiSel = (kq >> 1) != 0;   // m-half of node index s = kq*8+j

    // bpermute byte-index bases (lane_src * 4)
    const int idx_as_base = kqa * 32;            // + (h>>2)*64 + 4j
    const int idx_ad_base = 128 + r * 4;         // + (h>>2)*64
    const int idx_h_base  = (kqa * 32 + r) * 4;  // + (j>>2)*64

    // ---- A-frags straight from global: af{m}[ks] = X[16m+r][ks*32+kq*8 .. +7] ----
    bf16x8 af0[8], af1[8];
    const float* Xb = X + (size_t)b * (NNODE * DIN);
    {
        const float* xp0 = Xb + r * DIN + kq * 8;
#pragma unroll
        for (int ks = 0; ks < 8; ++ks) {
            const f32x4 x0 = *(const f32x4*)(xp0 + ks * 32);
            const f32x4 x1 = *(const f32x4*)(xp0 + ks * 32 + 4);
            bf16x8 v;
            v[0]=(__bf16)x0[0]; v[1]=(__bf16)x0[1]; v[2]=(__bf16)x0[2]; v[3]=(__bf16)x0[3];
            v[4]=(__bf16)x1[0]; v[5]=(__bf16)x1[1]; v[6]=(__bf16)x1[2]; v[7]=(__bf16)x1[3];
            af0[ks] = v;
        }
        const bool valid = r < 9;                 // rows 16+r must be < 25
        const float zm = valid ? 1.f : 0.f;
        const float* xp1 = Xb + (valid ? (16 + r) : r) * DIN + kq * 8;
#pragma unroll
        for (int ks = 0; ks < 8; ++ks) {
            const f32x4 x0 = *(const f32x4*)(xp1 + ks * 32);
            const f32x4 x1 = *(const f32x4*)(xp1 + ks * 32 + 4);
            bf16x8 v;
            v[0]=(__bf16)(x0[0]*zm); v[1]=(__bf16)(x0[1]*zm); v[2]=(__bf16)(x0[2]*zm); v[3]=(__bf16)(x0[3]*zm);
            v[4]=(__bf16)(x1[0]*zm); v[5]=(__bf16)(x1[1]*zm); v[6]=(__bf16)(x1[2]*zm); v[7]=(__bf16)(x1[3]*zm);
            af1[ks] = v;
        }
    }

    // ---- logits, swapped: L^T = Wa^T · X^T  =>  accL{m}[q] = L[16m+r][head-col 4kq+q] ----
    f32x4 accL0 = {0.f, 0.f, 0.f, 0.f};
    f32x4 accL1 = {0.f, 0.f, 0.f, 0.f};
#pragma unroll
    for (int ks = 0; ks < 8; ++ks) {
        const bf16x8 wa = *(const bf16x8*)(wf + ((size_t)(128 + ks) * 64 + l) * 8);
        accL0 = __builtin_amdgcn_mfma_f32_16x16x32_bf16(wa, af0[ks], accL0, 0, 0, 0);
        accL1 = __builtin_amdgcn_mfma_f32_16x16x32_bf16(wa, af1[ks], accL1, 0, 0, 0);
    }

    // ---- adjacency log-mults resident: lnm[d=dstt*16+r][s=kq*8+j] ----
    const f32x4 lnA0 = *(const f32x4*)(lnm + r * 32 + kq * 8);
    const f32x4 lnA1 = *(const f32x4*)(lnm + r * 32 + kq * 8 + 4);
    const f32x4 lnB0 = *(const f32x4*)(lnm + (16 + r) * 32 + kq * 8);
    const f32x4 lnB1 = *(const f32x4*)(lnm + (16 + r) * 32 + kq * 8 + 4);

    // ---- prefetch B-frags for tiles 0 (even buf) and 1 (odd buf) ----
    bf16x8 bwE[8], bwO[8];
#pragma unroll
    for (int ks = 0; ks < 8; ++ks)
        bwE[ks] = *(const bf16x8*)(wf + ((size_t)(0 * 8 + ks) * 64 + l) * 8);
#pragma unroll
    for (int ks = 0; ks < 8; ++ks)
        bwO[ks] = *(const bf16x8*)(wf + ((size_t)(1 * 8 + ks) * 64 + l) * 8);

    float* ob = out + (size_t)b * (NNODE * HF);

#pragma unroll
    for (int h = 0; h < 8; ++h) {
        // ---- softmax for head h (r8-verified) ----
        const int hb2 = (h >> 2) * 64;
        const int q   = h & 3;                      // static after unroll
        const float ad0 = bpermf(idx_ad_base + hb2, accL0[q]);   // L[d=r][8+h]
        const float ad1 = bpermf(idx_ad_base + hb2, accL1[q]);   // L[d=16+r][8+h]
        float e0[8], e1[8];
        float s0 = 0.f, s1 = 0.f;
#pragma unroll
        for (int j = 0; j < 8; ++j) {
            const int ia = idx_as_base + hb2 + j * 4;
            const float v0 = bpermf(ia, accL0[q]);
            const float v1 = bpermf(ia, accL1[q]);
            const float asj = hiSel ? v1 : v0;      // as[s = kq*8+j][h]
            const float ln0j = (j < 4) ? lnA0[j & 3] : lnA1[j & 3];
            const float ln1j = (j < 4) ? lnB0[j & 3] : lnB1[j & 3];
            float t0 = asj + ad0; t0 = (t0 > 0.f) ? t0 : NEG_SLOPE * t0;
            float t1 = asj + ad1; t1 = (t1 > 0.f) ? t1 : NEG_SLOPE * t1;
            e0[j] = __expf(t0 + ln0j);              // mult * exp(leaky), 0 if no edge
            e1[j] = __expf(t1 + ln1j);
            s0 += e0[j]; s1 += e1[j];
        }
        s0 += __shfl_xor(s0, 16); s0 += __shfl_xor(s0, 32);
        s1 += __shfl_xor(s1, 16); s1 += __shfl_xor(s1, 32);
        const float i0 = 1.f / (s0 + 1e-16f);
        const float i1 = 1.f / (s1 + 1e-16f);
        bf16x8 pf0, pf1;
#pragma unroll
        for (int j = 0; j < 8; ++j) {
            pf0[j] = (__bf16)(e0[j] * i0);
            pf1[j] = (__bf16)(e1[j] * i1);
        }

        // ---- cc = 0: tile ct = 2h from bwE; refill bwE <- 2h+2 right after use ----
        {
            const int ct = 2 * h;
            f32x4 a0 = {0.f, 0.f, 0.f, 0.f};
            f32x4 a1 = {0.f, 0.f, 0.f, 0.f};
#pragma unroll
            for (int ks = 0; ks < 8; ++ks) {
                a0 = __builtin_amdgcn_mfma_f32_16x16x32_bf16(af0[ks], bwE[ks], a0, 0, 0, 0);
                a1 = __builtin_amdgcn_mfma_f32_16x16x32_bf16(af1[ks], bwE[ks], a1, 0, 0, 0);
            }
            if (h < 7) {   // prefetch next even tile; consumed next head iter (~800 cyc away)
#pragma unroll
                for (int ks = 0; ks < 8; ++ks)
                    bwE[ks] = *(const bf16x8*)(wf + ((size_t)((ct + 2) * 8 + ks) * 64 + l) * 8);
            }
            // redistribute -> GEMM2 A-frag: hf[j] = h[s = kq*8+j][feat = ct*16+r]
            bf16x8 hf;
#pragma unroll
            for (int j = 0; j < 8; ++j) {
                const int ih = idx_h_base + (j >> 2) * 64;
                const float v0 = bpermf(ih, a0[j & 3]);
                const float v1 = bpermf(ih, a1[j & 3]);
                hf[j] = (__bf16)(hiSel ? v1 : v0);
            }
            const f32x4 bv = *(const f32x4*)(bias + ct * 16 + kq * 4);
            f32x4 o0 = bv, o1 = bv;
            o0 = __builtin_amdgcn_mfma_f32_16x16x32_bf16(hf, pf0, o0, 0, 0, 0);
            o1 = __builtin_amdgcn_mfma_f32_16x16x32_bf16(hf, pf1, o1, 0, 0, 0);
            *(f32x4*)(ob + r * HF + ct * 16 + kq * 4) = o0;
            if (r < 9)
                *(f32x4*)(ob + (16 + r) * HF + ct * 16 + kq * 4) = o1;
        }

        // ---- cc = 1: tile ct = 2h+1 from bwO; refill bwO <- 2h+3 right after use ----
        {
            const int ct = 2 * h + 1;
            f32x4 a0 = {0.f, 0.f, 0.f, 0.f};
            f32x4 a1 = {0.f, 0.f, 0.f, 0.f};
#pragma unroll
            for (int ks = 0; ks < 8; ++ks) {
                a0 = __builtin_amdgcn_mfma_f32_16x16x32_bf16(af0[ks], bwO[ks], a0, 0, 0, 0);
                a1 = __builtin_amdgcn_mfma_f32_16x16x32_bf16(af1[ks], bwO[ks], a1, 0, 0, 0);
            }
            if (h < 7) {
#pragma unroll
                for (int ks = 0; ks < 8; ++ks)
                    bwO[ks] = *(const bf16x8*)(wf + ((size_t)((ct + 2) * 8 + ks) * 64 + l) * 8);
            }
            bf16x8 hf;
#pragma unroll
            for (int j = 0; j < 8; ++j) {
                const int ih = idx_h_base + (j >> 2) * 64;
                const float v0 = bpermf(ih, a0[j & 3]);
                const float v1 = bpermf(ih, a1[j & 3]);
                hf[j] = (__bf16)(hiSel ? v1 : v0);
            }
            const f32x4 bv = *(const f32x4*)(bias + ct * 16 + kq * 4);
            f32x4 o0 = bv, o1 = bv;
            o0 = __builtin_amdgcn_mfma_f32_16x16x32_bf16(hf, pf0, o0, 0, 0, 0);
            o1 = __builtin_amdgcn_mfma_f32_16x16x32_bf16(hf, pf1, o1, 0, 0, 0);
            *(f32x4*)(ob + r * HF + ct * 16 + kq * 4) = o0;
            if (r < 9)
                *(f32x4*)(ob + (16 + r) * HF + ct * 16 + kq * 4) = o1;
        }
    }
}

extern "C" void kernel_launch(void* const* d_in, const int* in_sizes, int n_in,
                              void* d_out, int out_size, void* d_ws, size_t ws_size,
                              hipStream_t stream) {
    const float* X     = (const float*)d_in[0];
    const float* W     = (const float*)d_in[1];
    const float* a_src = (const float*)d_in[2];
    const float* a_dst = (const float*)d_in[3];
    const float* bias  = (const float*)d_in[4];
    const int*   edges = (const int*)d_in[5];
    float* out = (float*)d_out;
    unsigned short* wf = (unsigned short*)d_ws;
    float* lnm = (float*)((unsigned char*)d_ws + WS_LNM_OFF);

    hipLaunchKernelGGL(prep, dim3(35), dim3(256), 0, stream,
                       W, a_src, a_dst, edges, wf, lnm);
    hipLaunchKernelGGL(gat_wave, dim3(NBATCH / 4), dim3(256), 0, stream,
                       X, wf, lnm, bias, out);
}